// Round 3
// baseline (146.888 us; speedup 1.0000x reference)
//
#include <hip/hip_runtime.h>
#include <hip/hip_bf16.h>
#include <stdint.h>

#define NN 8192
#define DIN 256
#define HID 128
#define SCALE 0.08838834764831845f  // 1/(sqrt(128)*1.0)

typedef __attribute__((ext_vector_type(8))) short short8;
typedef __attribute__((ext_vector_type(4))) float f32x4;
typedef __attribute__((ext_vector_type(8))) unsigned short u16x8;
typedef __attribute__((ext_vector_type(4))) unsigned short u16x4;

__device__ __forceinline__ unsigned short f2bf(float f) {
  unsigned int u = __builtin_bit_cast(unsigned int, f);
  u += 0x7FFFu + ((u >> 16) & 1u);   // round-to-nearest-even
  return (unsigned short)(u >> 16);
}

__device__ __forceinline__ void async16(const void* g, void* l) {
  __builtin_amdgcn_global_load_lds(
      (const __attribute__((address_space(1))) unsigned int*)g,
      (__attribute__((address_space(3))) unsigned int*)l, 16, 0, 0);
}

// ---------------- Kernel W: weights -> bf16 transposed ----------------
__global__ __launch_bounds__(256) void kw0(
    const float* __restrict__ msg_w, const float* __restrict__ qw,
    const float* __restrict__ kw, const float* __restrict__ upd_w,
    unsigned short* __restrict__ mwT, unsigned short* __restrict__ qwT,
    unsigned short* __restrict__ kwT, unsigned short* __restrict__ w_t) {
  int idx0 = blockIdx.x * 1792 + threadIdx.x;
#pragma unroll
  for (int it = 0; it < 7; ++it) {
    int idx = idx0 + it * 256;
    if (idx < 32768) {                       // mwT
      int h = idx >> 8, j = idx & 255;
      mwT[idx] = f2bf(msg_w[j * HID + h]);
    } else if (idx < 49152) {                // qwT
      int r = idx - 32768, h = r >> 7, j = r & 127;
      qwT[r] = f2bf(qw[j * HID + h]);
    } else if (idx < 65536) {                // kwT
      int r = idx - 49152, h = r >> 7, j = r & 127;
      kwT[r] = f2bf(kw[j * HID + h]);
    } else {                                 // w_t
      int r = idx - 65536, h = r / 384, j = r % 384;
      w_t[r] = f2bf(upd_w[j * HID + h]);
    }
  }
}

// ---------------- Kernel A: messages, q, k via MFMA ----------------
__global__ __launch_bounds__(256) void ka(
    const float* __restrict__ nf, const unsigned short* __restrict__ mwT,
    const float* __restrict__ msg_b, const unsigned short* __restrict__ qwT,
    const unsigned short* __restrict__ kwT, unsigned short* __restrict__ q_bf,
    unsigned short* __restrict__ k_bf, unsigned short* __restrict__ m_t,
    unsigned short* __restrict__ nf_bf) {
  __shared__ __align__(16) unsigned short nfl[32][264];
  __shared__ __align__(16) unsigned short ml[32][136];
  int t = threadIdx.x, l = t & 63, w = t >> 6;
  int lr = l & 15, lg = l >> 4;
  int i0 = blockIdx.x * 32;
  {
    int row = t >> 3, c0 = (t & 7) * 32;
    const float* src = nf + (size_t)(i0 + row) * DIN + c0;
    unsigned short* gdst = nf_bf + (size_t)(i0 + row) * DIN + c0;
#pragma unroll
    for (int v = 0; v < 4; ++v) {
      f32x4 a = *(const f32x4*)(src + v * 8);
      f32x4 b = *(const f32x4*)(src + v * 8 + 4);
      u16x8 o;
#pragma unroll
      for (int e = 0; e < 4; ++e) { o[e] = f2bf(a[e]); o[4 + e] = f2bf(b[e]); }
      *(u16x8*)&nfl[row][c0 + v * 8] = o;
      *(u16x8*)(gdst + v * 8) = o;
    }
  }
  __syncthreads();
  int rl = (w >> 1) * 16;
  int nb = (w & 1) * 4;
  f32x4 macc[4];
#pragma unroll
  for (int nt = 0; nt < 4; ++nt) macc[nt] = (f32x4){0.f, 0.f, 0.f, 0.f};
#pragma unroll
  for (int kk = 0; kk < 8; ++kk) {
    short8 af = *(const short8*)&nfl[rl + lr][kk * 32 + lg * 8];
#pragma unroll
    for (int nt = 0; nt < 4; ++nt) {
      short8 bf = *(const short8*)(mwT + (size_t)((nb + nt) * 16 + lr) * DIN + kk * 32 + lg * 8);
      macc[nt] = __builtin_amdgcn_mfma_f32_16x16x32_bf16(af, bf, macc[nt], 0, 0, 0);
    }
  }
#pragma unroll
  for (int nt = 0; nt < 4; ++nt) {
    int col = (nb + nt) * 16 + lr;
    float bias = msg_b[col];
#pragma unroll
    for (int reg = 0; reg < 4; ++reg)
      ml[rl + lg * 4 + reg][col] = f2bf(macc[nt][reg] + bias);
  }
  __syncthreads();
  {
    int hh = t >> 1, i8 = (t & 1) * 16;
    u16x8 o0, o1;
#pragma unroll
    for (int v = 0; v < 8; ++v) { o0[v] = ml[i8 + v][hh]; o1[v] = ml[i8 + 8 + v][hh]; }
    *(u16x8*)(m_t + (size_t)hh * NN + i0 + i8) = o0;
    *(u16x8*)(m_t + (size_t)hh * NN + i0 + i8 + 8) = o1;
  }
  f32x4 qacc[4], kacc[4];
#pragma unroll
  for (int nt = 0; nt < 4; ++nt) {
    qacc[nt] = (f32x4){0.f, 0.f, 0.f, 0.f};
    kacc[nt] = (f32x4){0.f, 0.f, 0.f, 0.f};
  }
#pragma unroll
  for (int kk = 0; kk < 4; ++kk) {
    short8 af = *(const short8*)&ml[rl + lr][kk * 32 + lg * 8];
#pragma unroll
    for (int nt = 0; nt < 4; ++nt) {
      short8 bq = *(const short8*)(qwT + (size_t)((nb + nt) * 16 + lr) * HID + kk * 32 + lg * 8);
      short8 bk = *(const short8*)(kwT + (size_t)((nb + nt) * 16 + lr) * HID + kk * 32 + lg * 8);
      qacc[nt] = __builtin_amdgcn_mfma_f32_16x16x32_bf16(af, bq, qacc[nt], 0, 0, 0);
      kacc[nt] = __builtin_amdgcn_mfma_f32_16x16x32_bf16(af, bk, kacc[nt], 0, 0, 0);
    }
  }
#pragma unroll
  for (int nt = 0; nt < 4; ++nt) {
    int col = (nb + nt) * 16 + lr;
#pragma unroll
    for (int reg = 0; reg < 4; ++reg) {
      int row = i0 + rl + lg * 4 + reg;
      q_bf[(size_t)row * HID + col] = f2bf(qacc[nt][reg]);
      k_bf[(size_t)row * HID + col] = f2bf(kacc[nt][reg]);
    }
  }
}

// ---------------- Kernel B: fused gate + aggregate, software-pipelined ----------------
// grid (128, 8): bx = 64-row tile, by = 1024-col j-chunk; XCD-chunk swizzled.
// Pipeline per jt: STAGE(k,m @ jt) | prefetch adj(jt+1)->regs | vmcnt(16) |
// s_barrier | compute(jt) | s_barrier.  vmcnt never drained to 0 in-loop (T4).
__global__ __launch_bounds__(256, 4) void kb(
    const unsigned short* __restrict__ q_bf, const unsigned short* __restrict__ k_bf,
    const unsigned short* __restrict__ m_t, const float* __restrict__ adj,
    const float* __restrict__ gate_bias, float* __restrict__ agg_parts) {
  __shared__ __align__(16) char klds[16384];   // k tile [64][128] bf16, swizzled
  __shared__ __align__(16) char mlds[16384];   // mT tile [128][64] bf16, swizzled
  __shared__ __align__(16) char glds[8192];    // gates [4 waves][16][64] bf16, swizzled
  int t = threadIdx.x, l = t & 63, w = t >> 6;
  int lr = l & 15, lg = l >> 4;
  int lin = blockIdx.x + blockIdx.y * 128;
  int nlin = (lin & 7) * 128 + (lin >> 3);
  int bx = nlin & 127, by = nlin >> 7;
  int i0 = bx * 64;
  int jbase = by * 1024;
  float gb = gate_bias[0];

  int qrow = i0 + w * 16 + lr;
  short8 qf[4];
#pragma unroll
  for (int kk = 0; kk < 4; ++kk)
    qf[kk] = *(const short8*)(q_bf + (size_t)qrow * HID + kk * 32 + lg * 8);

  // per-thread constant staging offsets
  int krow = t >> 4;                         // 0..15 within p-stripe of 16 rows
  int klb = (t & 15) ^ (krow & 7);
  int mrow_s = t >> 3;                       // 0..31 within p-stripe of 32 rows
  int mlb = (t & 7) ^ (mrow_s & 7);

  // adj row base pointers (one per reg)
  const float* arow[4];
#pragma unroll
  for (int reg = 0; reg < 4; ++reg)
    arow[reg] = adj + (size_t)(i0 + w * 16 + lg * 4 + reg) * NN + lr;

  f32x4 acc[8];
#pragma unroll
  for (int nt = 0; nt < 8; ++nt) acc[nt] = (f32x4){0.f, 0.f, 0.f, 0.f};

  float adjv[2][4][4];
  // prologue: adj(0)
#pragma unroll
  for (int jt16 = 0; jt16 < 4; ++jt16)
#pragma unroll
    for (int reg = 0; reg < 4; ++reg)
      adjv[0][jt16][reg] = arow[reg][jbase + jt16 * 16];

#pragma unroll 2
  for (int jt = 0; jt < 16; ++jt) {
    const int cur = jt & 1;
    int j0 = jbase + jt * 64;
    // ---- STAGE k,m tile jt (8 gload_lds / wave) ----
#pragma unroll
    for (int p = 0; p < 4; ++p)
      async16(k_bf + (size_t)(j0 + p * 16 + krow) * HID + klb * 8,
              klds + p * 4096 + w * 1024);
#pragma unroll
    for (int p = 0; p < 4; ++p)
      async16(m_t + (size_t)(p * 32 + mrow_s) * NN + j0 + mlb * 8,
              mlds + p * 4096 + w * 1024);
    // pin issue order: stages strictly older than adj prefetch
    asm volatile("" ::: "memory");
    // ---- prefetch adj(jt+1) -> regs (stays in flight across compute) ----
    {
      int jn0 = jbase + (jt < 15 ? jt + 1 : jt) * 64;
#pragma unroll
      for (int jt16 = 0; jt16 < 4; ++jt16)
#pragma unroll
        for (int reg = 0; reg < 4; ++reg)
          adjv[cur ^ 1][jt16][reg] = arow[reg][jn0 + jt16 * 16];
    }
    // wait: stages(8) + adj(jt) retired; adj(jt+1)(16) still flying
    asm volatile("s_waitcnt vmcnt(16)" ::: "memory");
    __builtin_amdgcn_s_barrier();

    // ---- compute(jt): S = q@k^T ; gate ; PV ----
#pragma unroll
    for (int jt16 = 0; jt16 < 4; ++jt16) {
      f32x4 s_acc = (f32x4){0.f, 0.f, 0.f, 0.f};
#pragma unroll
      for (int kk = 0; kk < 4; ++kk) {
        int row = jt16 * 16 + lr;
        int blk = kk * 4 + lg;
        const short8 bf = *(const short8*)(klds + row * 256 + ((blk ^ (row & 7)) * 16));
        s_acc = __builtin_amdgcn_mfma_f32_16x16x32_bf16(qf[kk], bf, s_acc, 0, 0, 0);
      }
#pragma unroll
      for (int reg = 0; reg < 4; ++reg) {
        float x = s_acc[reg] * SCALE + gb;
        float e = __expf(-x);
        float g = adjv[cur][jt16][reg] * __builtin_amdgcn_rcpf(1.0f + e);
        int row = lg * 4 + reg;
        int colb = (jt16 * 16 + lr) * 2;
        *(unsigned short*)(glds + w * 2048 + row * 128 + (colb ^ ((row & 7) << 4))) =
            f2bf(g);
      }
    }
#pragma unroll
    for (int kk2 = 0; kk2 < 2; ++kk2) {
      short8 af = *(const short8*)(glds + w * 2048 + lr * 128 +
                                   ((kk2 * 64 + lg * 16) ^ ((lr & 7) << 4)));
#pragma unroll
      for (int nt = 0; nt < 8; ++nt) {
        int mrow = nt * 16 + lr;
        int blk = kk2 * 4 + lg;
        const short8 bf =
            *(const short8*)(mlds + mrow * 128 + ((blk ^ (mrow & 7)) * 16));
        acc[nt] = __builtin_amdgcn_mfma_f32_16x16x32_bf16(af, bf, acc[nt], 0, 0, 0);
      }
    }
    __builtin_amdgcn_s_barrier();  // klds/mlds free for next STAGE
  }
  float* part = agg_parts + (size_t)by * NN * HID;
#pragma unroll
  for (int nt = 0; nt < 8; ++nt)
#pragma unroll
    for (int reg = 0; reg < 4; ++reg)
      part[(size_t)(i0 + w * 16 + lg * 4 + reg) * HID + nt * 16 + lr] = acc[nt][reg];
}

// ---------------- Kernel C: update GEMM + ReLU + LayerNorm ----------------
__global__ __launch_bounds__(256) void kc(
    const unsigned short* __restrict__ nf_bf, const float* __restrict__ agg_parts,
    const unsigned short* __restrict__ w_t, const float* __restrict__ upd_b,
    const float* __restrict__ gamma, const float* __restrict__ beta,
    float* __restrict__ out) {
  __shared__ __align__(16) unsigned short aggl[64][136];
  int t = threadIdx.x, l = t & 63, w = t >> 6;
  int i0 = blockIdx.x * 64;
  {
    const f32x4* p0 = (const f32x4*)(agg_parts + (size_t)i0 * HID);
    const size_t ps = (size_t)NN * HID / 4;
    for (int e = t; e < 64 * HID / 4; e += 256) {
      f32x4 s = p0[e];
#pragma unroll
      for (int c = 1; c < 8; ++c) s += p0[e + c * ps];
      int row = (e * 4) / HID, col = (e * 4) % HID;
      u16x4 o;
#pragma unroll
      for (int v = 0; v < 4; ++v) o[v] = f2bf(s[v]);
      *(u16x4*)&aggl[row][col] = o;
    }
  }
  __syncthreads();
  int lr = l & 15, lg = l >> 4;
  int arow = i0 + w * 16 + lr;
  short8 af[12];
#pragma unroll
  for (int kk = 0; kk < 8; ++kk)
    af[kk] = *(const short8*)(nf_bf + (size_t)arow * DIN + kk * 32 + lg * 8);
#pragma unroll
  for (int kk = 8; kk < 12; ++kk)
    af[kk] = *(const short8*)(&aggl[w * 16 + lr][(kk - 8) * 32 + lg * 8]);
  f32x4 acc[8];
#pragma unroll
  for (int nt = 0; nt < 8; ++nt) acc[nt] = (f32x4){0.f, 0.f, 0.f, 0.f};
#pragma unroll
  for (int kk = 0; kk < 12; ++kk)
#pragma unroll
    for (int nt = 0; nt < 8; ++nt) {
      const short8 bf =
          *(const short8*)(w_t + (size_t)(nt * 16 + lr) * 384 + kk * 32 + lg * 8);
      acc[nt] = __builtin_amdgcn_mfma_f32_16x16x32_bf16(af[kk], bf, acc[nt], 0, 0, 0);
    }
  float ub[8], ga[8], be[8];
#pragma unroll
  for (int nt = 0; nt < 8; ++nt) {
    ub[nt] = upd_b[nt * 16 + lr];
    ga[nt] = gamma[nt * 16 + lr];
    be[nt] = beta[nt * 16 + lr];
  }
  float v[8][4], sum[4], sq[4];
#pragma unroll
  for (int reg = 0; reg < 4; ++reg) { sum[reg] = 0.f; sq[reg] = 0.f; }
#pragma unroll
  for (int nt = 0; nt < 8; ++nt)
#pragma unroll
    for (int reg = 0; reg < 4; ++reg) {
      float x = acc[nt][reg] + ub[nt];
      x = fmaxf(x, 0.f);
      v[nt][reg] = x;
      sum[reg] += x;
      sq[reg] = fmaf(x, x, sq[reg]);
    }
#pragma unroll
  for (int reg = 0; reg < 4; ++reg) {
#pragma unroll
    for (int m = 1; m < 16; m <<= 1) {
      sum[reg] += __shfl_xor(sum[reg], m, 16);
      sq[reg] += __shfl_xor(sq[reg], m, 16);
    }
  }
#pragma unroll
  for (int reg = 0; reg < 4; ++reg) {
    float mu = sum[reg] * (1.0f / 128.0f);
    float var = sq[reg] * (1.0f / 128.0f) - mu * mu;
    float rstd = rsqrtf(var + 1e-5f);
    int orow = i0 + w * 16 + lg * 4 + reg;
#pragma unroll
    for (int nt = 0; nt < 8; ++nt) {
      float y = (v[nt][reg] - mu) * rstd * ga[nt] + be[nt];
      out[(size_t)orow * HID + nt * 16 + lr] = y;
    }
  }
}

extern "C" void kernel_launch(void* const* d_in, const int* in_sizes, int n_in,
                              void* d_out, int out_size, void* d_ws, size_t ws_size,
                              hipStream_t stream) {
  const float* nf    = (const float*)d_in[0];
  const float* adj   = (const float*)d_in[1];
  const float* msg_w = (const float*)d_in[2];
  const float* msg_b = (const float*)d_in[3];
  const float* upd_w = (const float*)d_in[4];
  const float* upd_b = (const float*)d_in[5];
  const float* qw    = (const float*)d_in[6];
  const float* kw    = (const float*)d_in[7];
  const float* gbias = (const float*)d_in[8];
  const float* gamma = (const float*)d_in[9];
  const float* beta  = (const float*)d_in[10];
  char* ws = (char*)d_ws;
  unsigned short* q_bf  = (unsigned short*)(ws);              // 2 MB
  unsigned short* k_bf  = (unsigned short*)(ws + 0x200000);   // 2 MB
  unsigned short* m_t   = (unsigned short*)(ws + 0x400000);   // 2 MB
  unsigned short* nf_bf = (unsigned short*)(ws + 0x600000);   // 4 MB
  unsigned short* w_t   = (unsigned short*)(ws + 0xA00000);   // 96 KB
  unsigned short* mwT   = (unsigned short*)(ws + 0xA20000);   // 64 KB
  unsigned short* qwT   = (unsigned short*)(ws + 0xA30000);   // 32 KB
  unsigned short* kwT   = (unsigned short*)(ws + 0xA38000);   // 32 KB
  float* agg            = (float*)(ws + 0xA40000);            // 8 x 4 MB

  kw0<<<64, 256, 0, stream>>>(msg_w, qw, kw, upd_w, mwT, qwT, kwT, w_t);
  ka<<<256, 256, 0, stream>>>(nf, mwT, msg_b, qwT, kwT, q_bf, k_bf, m_t, nf_bf);
  kb<<<dim3(128, 8), 256, 0, stream>>>(q_bf, k_bf, m_t, adj, gbias, agg);
  kc<<<128, 256, 0, stream>>>(nf_bf, agg, w_t, upd_b, gamma, beta, (float*)d_out);
}

// Round 4
// 141.989 us; speedup vs baseline: 1.0345x; 1.0345x over previous
//
#include <hip/hip_runtime.h>
#include <hip/hip_bf16.h>
#include <stdint.h>

#define NN 8192
#define DIN 256
#define HID 128
#define SCALE 0.08838834764831845f  // 1/(sqrt(128)*1.0)

typedef __attribute__((ext_vector_type(8))) short short8;
typedef __attribute__((ext_vector_type(4))) float f32x4;
typedef __attribute__((ext_vector_type(8))) unsigned short u16x8;
typedef __attribute__((ext_vector_type(4))) unsigned short u16x4;

__device__ __forceinline__ unsigned short f2bf(float f) {
  unsigned int u = __builtin_bit_cast(unsigned int, f);
  u += 0x7FFFu + ((u >> 16) & 1u);   // round-to-nearest-even
  return (unsigned short)(u >> 16);
}

__device__ __forceinline__ void async16(const void* g, void* l) {
  __builtin_amdgcn_global_load_lds(
      (const __attribute__((address_space(1))) unsigned int*)g,
      (__attribute__((address_space(3))) unsigned int*)l, 16, 0, 0);
}

// ---------------- Kernel W: weights -> bf16 transposed ----------------
__global__ __launch_bounds__(256) void kw0(
    const float* __restrict__ msg_w, const float* __restrict__ qw,
    const float* __restrict__ kw, const float* __restrict__ upd_w,
    unsigned short* __restrict__ mwT, unsigned short* __restrict__ qwT,
    unsigned short* __restrict__ kwT, unsigned short* __restrict__ w_t) {
  int idx0 = blockIdx.x * 1792 + threadIdx.x;
#pragma unroll
  for (int it = 0; it < 7; ++it) {
    int idx = idx0 + it * 256;
    if (idx < 32768) {                       // mwT
      int h = idx >> 8, j = idx & 255;
      mwT[idx] = f2bf(msg_w[j * HID + h]);
    } else if (idx < 49152) {                // qwT
      int r = idx - 32768, h = r >> 7, j = r & 127;
      qwT[r] = f2bf(qw[j * HID + h]);
    } else if (idx < 65536) {                // kwT
      int r = idx - 49152, h = r >> 7, j = r & 127;
      kwT[r] = f2bf(kw[j * HID + h]);
    } else {                                 // w_t
      int r = idx - 65536, h = r / 384, j = r % 384;
      w_t[r] = f2bf(upd_w[j * HID + h]);
    }
  }
}

// ---------------- Kernel A: messages, q, k via MFMA ----------------
__global__ __launch_bounds__(256) void ka(
    const float* __restrict__ nf, const unsigned short* __restrict__ mwT,
    const float* __restrict__ msg_b, const unsigned short* __restrict__ qwT,
    const unsigned short* __restrict__ kwT, unsigned short* __restrict__ q_bf,
    unsigned short* __restrict__ k_bf, unsigned short* __restrict__ m_t,
    unsigned short* __restrict__ nf_bf) {
  __shared__ __align__(16) unsigned short nfl[32][264];
  __shared__ __align__(16) unsigned short ml[32][136];
  int t = threadIdx.x, l = t & 63, w = t >> 6;
  int lr = l & 15, lg = l >> 4;
  int i0 = blockIdx.x * 32;
  {
    int row = t >> 3, c0 = (t & 7) * 32;
    const float* src = nf + (size_t)(i0 + row) * DIN + c0;
    unsigned short* gdst = nf_bf + (size_t)(i0 + row) * DIN + c0;
#pragma unroll
    for (int v = 0; v < 4; ++v) {
      f32x4 a = *(const f32x4*)(src + v * 8);
      f32x4 b = *(const f32x4*)(src + v * 8 + 4);
      u16x8 o;
#pragma unroll
      for (int e = 0; e < 4; ++e) { o[e] = f2bf(a[e]); o[4 + e] = f2bf(b[e]); }
      *(u16x8*)&nfl[row][c0 + v * 8] = o;
      *(u16x8*)(gdst + v * 8) = o;
    }
  }
  __syncthreads();
  int rl = (w >> 1) * 16;
  int nb = (w & 1) * 4;
  f32x4 macc[4];
#pragma unroll
  for (int nt = 0; nt < 4; ++nt) macc[nt] = (f32x4){0.f, 0.f, 0.f, 0.f};
#pragma unroll
  for (int kk = 0; kk < 8; ++kk) {
    short8 af = *(const short8*)&nfl[rl + lr][kk * 32 + lg * 8];
#pragma unroll
    for (int nt = 0; nt < 4; ++nt) {
      short8 bf = *(const short8*)(mwT + (size_t)((nb + nt) * 16 + lr) * DIN + kk * 32 + lg * 8);
      macc[nt] = __builtin_amdgcn_mfma_f32_16x16x32_bf16(af, bf, macc[nt], 0, 0, 0);
    }
  }
#pragma unroll
  for (int nt = 0; nt < 4; ++nt) {
    int col = (nb + nt) * 16 + lr;
    float bias = msg_b[col];
#pragma unroll
    for (int reg = 0; reg < 4; ++reg)
      ml[rl + lg * 4 + reg][col] = f2bf(macc[nt][reg] + bias);
  }
  __syncthreads();
  {
    int hh = t >> 1, i8 = (t & 1) * 16;
    u16x8 o0, o1;
#pragma unroll
    for (int v = 0; v < 8; ++v) { o0[v] = ml[i8 + v][hh]; o1[v] = ml[i8 + 8 + v][hh]; }
    *(u16x8*)(m_t + (size_t)hh * NN + i0 + i8) = o0;
    *(u16x8*)(m_t + (size_t)hh * NN + i0 + i8 + 8) = o1;
  }
  f32x4 qacc[4], kacc[4];
#pragma unroll
  for (int nt = 0; nt < 4; ++nt) {
    qacc[nt] = (f32x4){0.f, 0.f, 0.f, 0.f};
    kacc[nt] = (f32x4){0.f, 0.f, 0.f, 0.f};
  }
#pragma unroll
  for (int kk = 0; kk < 4; ++kk) {
    short8 af = *(const short8*)&ml[rl + lr][kk * 32 + lg * 8];
#pragma unroll
    for (int nt = 0; nt < 4; ++nt) {
      short8 bq = *(const short8*)(qwT + (size_t)((nb + nt) * 16 + lr) * HID + kk * 32 + lg * 8);
      short8 bk = *(const short8*)(kwT + (size_t)((nb + nt) * 16 + lr) * HID + kk * 32 + lg * 8);
      qacc[nt] = __builtin_amdgcn_mfma_f32_16x16x32_bf16(af, bq, qacc[nt], 0, 0, 0);
      kacc[nt] = __builtin_amdgcn_mfma_f32_16x16x32_bf16(af, bk, kacc[nt], 0, 0, 0);
    }
  }
#pragma unroll
  for (int nt = 0; nt < 4; ++nt) {
    int col = (nb + nt) * 16 + lr;
#pragma unroll
    for (int reg = 0; reg < 4; ++reg) {
      int row = i0 + rl + lg * 4 + reg;
      q_bf[(size_t)row * HID + col] = f2bf(qacc[nt][reg]);
      k_bf[(size_t)row * HID + col] = f2bf(kacc[nt][reg]);
    }
  }
}

// ---------------- Kernel B: fused gate + aggregate, dbuf + counted vmcnt ----------------
// grid (128, 8), XCD-chunk swizzled. Per jt:
//   adj(jt) [16 VMEM, oldest] | stage(jt+1)->buf^1 [8 gload_lds] |
//   vmcnt(24) = drain stage(jt) only | s_barrier | compute(jt) | s_barrier.
// Gate's adj use waits vmcnt(8): stage(jt+1) stays in flight across compute (T4).
// Iter 15 redundantly re-stages tile 0 into the dead buffer -> uniform vmcnt(24).
__global__ __launch_bounds__(256, 2) void kb(
    const unsigned short* __restrict__ q_bf, const unsigned short* __restrict__ k_bf,
    const unsigned short* __restrict__ m_t, const float* __restrict__ adj,
    const float* __restrict__ gate_bias, float* __restrict__ agg_parts) {
  __shared__ __align__(16) char klds[2][16384];  // k tile [64][128] bf16, swizzled
  __shared__ __align__(16) char mlds[2][16384];  // mT tile [128][64] bf16, swizzled
  __shared__ __align__(16) char glds[8192];      // gates [4 waves][16][64] bf16, swizzled
  int t = threadIdx.x, l = t & 63, w = t >> 6;
  int lr = l & 15, lg = l >> 4;
  int lin = blockIdx.x + blockIdx.y * 128;
  int nlin = (lin & 7) * 128 + (lin >> 3);
  int bx = nlin & 127, by = nlin >> 7;
  int i0 = bx * 64;
  int jbase = by * 1024;
  float gb = gate_bias[0];

  int qrow = i0 + w * 16 + lr;
  short8 qf[4];
#pragma unroll
  for (int kk = 0; kk < 4; ++kk)
    qf[kk] = *(const short8*)(q_bf + (size_t)qrow * HID + kk * 32 + lg * 8);

  // per-thread constant staging offsets
  int krow = t >> 4;                         // 0..15 within 16-row p-stripe
  int klb = (t & 15) ^ (krow & 7);
  int mrow_s = t >> 3;                       // 0..31 within 32-row p-stripe
  int mlb = (t & 7) ^ (mrow_s & 7);

  const float* arow[4];
#pragma unroll
  for (int reg = 0; reg < 4; ++reg)
    arow[reg] = adj + (size_t)(i0 + w * 16 + lg * 4 + reg) * NN + lr;

  f32x4 acc[8];
#pragma unroll
  for (int nt = 0; nt < 8; ++nt) acc[nt] = (f32x4){0.f, 0.f, 0.f, 0.f};

  // prologue: stage tile 0 -> buf 0  (8 outstanding at loop entry)
  {
    int j0 = jbase;
#pragma unroll
    for (int p = 0; p < 4; ++p)
      async16(k_bf + (size_t)(j0 + p * 16 + krow) * HID + klb * 8,
              &klds[0][p * 4096 + w * 1024]);
#pragma unroll
    for (int p = 0; p < 4; ++p)
      async16(m_t + (size_t)(p * 32 + mrow_s) * NN + j0 + mlb * 8,
              &mlds[0][p * 4096 + w * 1024]);
  }

  for (int jt = 0; jt < 16; ++jt) {
    int j0 = jbase + jt * 64;
    const char* kcur = &klds[jt & 1][0];
    const char* mcur = &mlds[jt & 1][0];
    // ---- adj(jt) first (oldest in vmcnt stream) ----
    float adjv[4][4];
#pragma unroll
    for (int jt16 = 0; jt16 < 4; ++jt16)
#pragma unroll
      for (int reg = 0; reg < 4; ++reg)
        adjv[jt16][reg] = arow[reg][j0 + jt16 * 16];
    asm volatile("" ::: "memory");  // pin: adj strictly older than stage
    // ---- stage(jt+1) -> other buffer ----
    {
      int jn = (jt + 1) & 15;
      int j0n = jbase + jn * 64;
      char* knxt = &klds[(jt + 1) & 1][0];
      char* mnxt = &mlds[(jt + 1) & 1][0];
#pragma unroll
      for (int p = 0; p < 4; ++p)
        async16(k_bf + (size_t)(j0n + p * 16 + krow) * HID + klb * 8,
                knxt + p * 4096 + w * 1024);
#pragma unroll
      for (int p = 0; p < 4; ++p)
        async16(m_t + (size_t)(p * 32 + mrow_s) * NN + j0n + mlb * 8,
                mnxt + p * 4096 + w * 1024);
    }
    // drain exactly stage(jt): outstanding = stage(jt)8 + adj16 + stage(jt+1)8
    asm volatile("s_waitcnt vmcnt(24)" ::: "memory");
    __builtin_amdgcn_s_barrier();
    __builtin_amdgcn_sched_barrier(0);

    // ---- compute(jt): S = q@k^T ; gate ; PV ----
#pragma unroll
    for (int jt16 = 0; jt16 < 4; ++jt16) {
      f32x4 s_acc = (f32x4){0.f, 0.f, 0.f, 0.f};
#pragma unroll
      for (int kk = 0; kk < 4; ++kk) {
        int row = jt16 * 16 + lr;
        int blk = kk * 4 + lg;
        const short8 bf = *(const short8*)(kcur + row * 256 + ((blk ^ (row & 7)) * 16));
        s_acc = __builtin_amdgcn_mfma_f32_16x16x32_bf16(qf[kk], bf, s_acc, 0, 0, 0);
      }
#pragma unroll
      for (int reg = 0; reg < 4; ++reg) {
        float x = s_acc[reg] * SCALE + gb;
        float e = __expf(-x);
        float g = adjv[jt16][reg] * __builtin_amdgcn_rcpf(1.0f + e);
        int row = lg * 4 + reg;
        int colb = (jt16 * 16 + lr) * 2;
        *(unsigned short*)(glds + w * 2048 + row * 128 + (colb ^ ((row & 7) << 4))) =
            f2bf(g);
      }
    }
#pragma unroll
    for (int kk2 = 0; kk2 < 2; ++kk2) {
      short8 af = *(const short8*)(glds + w * 2048 + lr * 128 +
                                   ((kk2 * 64 + lg * 16) ^ ((lr & 7) << 4)));
#pragma unroll
      for (int nt = 0; nt < 8; ++nt) {
        int mrow = nt * 16 + lr;
        int blk = kk2 * 4 + lg;
        const short8 bf =
            *(const short8*)(mcur + mrow * 128 + ((blk ^ (mrow & 7)) * 16));
        acc[nt] = __builtin_amdgcn_mfma_f32_16x16x32_bf16(af, bf, acc[nt], 0, 0, 0);
      }
    }
    __builtin_amdgcn_sched_barrier(0);
    __builtin_amdgcn_s_barrier();  // all waves done reading buf[jt&1]
  }
  float* part = agg_parts + (size_t)by * NN * HID;
#pragma unroll
  for (int nt = 0; nt < 8; ++nt)
#pragma unroll
    for (int reg = 0; reg < 4; ++reg)
      part[(size_t)(i0 + w * 16 + lg * 4 + reg) * HID + nt * 16 + lr] = acc[nt][reg];
}

// ---------------- Kernel C: update GEMM + ReLU + LayerNorm ----------------
__global__ __launch_bounds__(256) void kc(
    const unsigned short* __restrict__ nf_bf, const float* __restrict__ agg_parts,
    const unsigned short* __restrict__ w_t, const float* __restrict__ upd_b,
    const float* __restrict__ gamma, const float* __restrict__ beta,
    float* __restrict__ out) {
  __shared__ __align__(16) unsigned short aggl[64][136];
  int t = threadIdx.x, l = t & 63, w = t >> 6;
  int i0 = blockIdx.x * 64;
  {
    const f32x4* p0 = (const f32x4*)(agg_parts + (size_t)i0 * HID);
    const size_t ps = (size_t)NN * HID / 4;
    for (int e = t; e < 64 * HID / 4; e += 256) {
      f32x4 s = p0[e];
#pragma unroll
      for (int c = 1; c < 8; ++c) s += p0[e + c * ps];
      int row = (e * 4) / HID, col = (e * 4) % HID;
      u16x4 o;
#pragma unroll
      for (int v = 0; v < 4; ++v) o[v] = f2bf(s[v]);
      *(u16x4*)&aggl[row][col] = o;
    }
  }
  __syncthreads();
  int lr = l & 15, lg = l >> 4;
  int arow = i0 + w * 16 + lr;
  short8 af[12];
#pragma unroll
  for (int kk = 0; kk < 8; ++kk)
    af[kk] = *(const short8*)(nf_bf + (size_t)arow * DIN + kk * 32 + lg * 8);
#pragma unroll
  for (int kk = 8; kk < 12; ++kk)
    af[kk] = *(const short8*)(&aggl[w * 16 + lr][(kk - 8) * 32 + lg * 8]);
  f32x4 acc[8];
#pragma unroll
  for (int nt = 0; nt < 8; ++nt) acc[nt] = (f32x4){0.f, 0.f, 0.f, 0.f};
#pragma unroll
  for (int kk = 0; kk < 12; ++kk)
#pragma unroll
    for (int nt = 0; nt < 8; ++nt) {
      const short8 bf =
          *(const short8*)(w_t + (size_t)(nt * 16 + lr) * 384 + kk * 32 + lg * 8);
      acc[nt] = __builtin_amdgcn_mfma_f32_16x16x32_bf16(af[kk], bf, acc[nt], 0, 0, 0);
    }
  float ub[8], ga[8], be[8];
#pragma unroll
  for (int nt = 0; nt < 8; ++nt) {
    ub[nt] = upd_b[nt * 16 + lr];
    ga[nt] = gamma[nt * 16 + lr];
    be[nt] = beta[nt * 16 + lr];
  }
  float v[8][4], sum[4], sq[4];
#pragma unroll
  for (int reg = 0; reg < 4; ++reg) { sum[reg] = 0.f; sq[reg] = 0.f; }
#pragma unroll
  for (int nt = 0; nt < 8; ++nt)
#pragma unroll
    for (int reg = 0; reg < 4; ++reg) {
      float x = acc[nt][reg] + ub[nt];
      x = fmaxf(x, 0.f);
      v[nt][reg] = x;
      sum[reg] += x;
      sq[reg] = fmaf(x, x, sq[reg]);
    }
#pragma unroll
  for (int reg = 0; reg < 4; ++reg) {
#pragma unroll
    for (int m = 1; m < 16; m <<= 1) {
      sum[reg] += __shfl_xor(sum[reg], m, 16);
      sq[reg] += __shfl_xor(sq[reg], m, 16);
    }
  }
#pragma unroll
  for (int reg = 0; reg < 4; ++reg) {
    float mu = sum[reg] * (1.0f / 128.0f);
    float var = sq[reg] * (1.0f / 128.0f) - mu * mu;
    float rstd = rsqrtf(var + 1e-5f);
    int orow = i0 + w * 16 + lg * 4 + reg;
#pragma unroll
    for (int nt = 0; nt < 8; ++nt) {
      float y = (v[nt][reg] - mu) * rstd * ga[nt] + be[nt];
      out[(size_t)orow * HID + nt * 16 + lr] = y;
    }
  }
}

extern "C" void kernel_launch(void* const* d_in, const int* in_sizes, int n_in,
                              void* d_out, int out_size, void* d_ws, size_t ws_size,
                              hipStream_t stream) {
  const float* nf    = (const float*)d_in[0];
  const float* adj   = (const float*)d_in[1];
  const float* msg_w = (const float*)d_in[2];
  const float* msg_b = (const float*)d_in[3];
  const float* upd_w = (const float*)d_in[4];
  const float* upd_b = (const float*)d_in[5];
  const float* qw    = (const float*)d_in[6];
  const float* kw    = (const float*)d_in[7];
  const float* gbias = (const float*)d_in[8];
  const float* gamma = (const float*)d_in[9];
  const float* beta  = (const float*)d_in[10];
  char* ws = (char*)d_ws;
  unsigned short* q_bf  = (unsigned short*)(ws);              // 2 MB
  unsigned short* k_bf  = (unsigned short*)(ws + 0x200000);   // 2 MB
  unsigned short* m_t   = (unsigned short*)(ws + 0x400000);   // 2 MB
  unsigned short* nf_bf = (unsigned short*)(ws + 0x600000);   // 4 MB
  unsigned short* w_t   = (unsigned short*)(ws + 0xA00000);   // 96 KB
  unsigned short* mwT   = (unsigned short*)(ws + 0xA20000);   // 64 KB
  unsigned short* qwT   = (unsigned short*)(ws + 0xA30000);   // 32 KB
  unsigned short* kwT   = (unsigned short*)(ws + 0xA38000);   // 32 KB
  float* agg            = (float*)(ws + 0xA40000);            // 8 x 4 MB

  kw0<<<64, 256, 0, stream>>>(msg_w, qw, kw, upd_w, mwT, qwT, kwT, w_t);
  ka<<<256, 256, 0, stream>>>(nf, mwT, msg_b, qwT, kwT, q_bf, k_bf, m_t, nf_bf);
  kb<<<dim3(128, 8), 256, 0, stream>>>(q_bf, k_bf, m_t, adj, gbias, agg);
  kc<<<128, 256, 0, stream>>>(nf_bf, agg, w_t, upd_b, gamma, beta, (float*)d_out);
}